// Round 7
// baseline (119.569 us; speedup 1.0000x reference)
//
#include <hip/hip_runtime.h>
#include <hip/hip_bf16.h>
#include <math.h>

#define D_DIM 512
#define TB    256          // symmetric tile (R21)

typedef int i32x4 __attribute__((ext_vector_type(4)));
typedef unsigned long long u64;

// ---- helpers ---------------------------------------------------------------

__device__ inline void async16(unsigned char* lds, const unsigned char* g) {
    __builtin_amdgcn_global_load_lds(
        (const __attribute__((address_space(1))) void*)g,
        (__attribute__((address_space(3))) void*)lds,
        16, 0, 0);
}

// ---- kernel 1: row L2-normalize -> int8 (x127) in K-MAJOR layout -----------
// X_t layout: [kc:8][slot:4][row:8192][16B]  (kc = 64-col chunk, slot = 16B
// sub-chunk). A GEMM K-step stage of a 256-row band is then 8 CONTIGUOUS
// 4 KB segments instead of 256 scattered 64B segments (R21 theory: the
// ~20 GB/s/CU ingest wall across R15-R20 is VMEM scatter, not cache BW).

__global__ __launch_bounds__(256) void normalize_rows(
        const float* __restrict__ in, unsigned char* __restrict__ xb,
        float* __restrict__ inv_norm, u64* __restrict__ best,
        float* __restrict__ acc, int* __restrict__ cnt) {
    const int row  = blockIdx.x * 4 + (threadIdx.x >> 6);
    const int lane = threadIdx.x & 63;
    if (blockIdx.x == 0 && threadIdx.x == 0) { acc[0] = 0.f; cnt[0] = 0; }
    const float4* rp = (const float4*)(in + (size_t)row * D_DIM) + lane * 2;
    float4 a = rp[0], b = rp[1];
    float s = a.x*a.x + a.y*a.y + a.z*a.z + a.w*a.w
            + b.x*b.x + b.y*b.y + b.z*b.z + b.w*b.w;
    #pragma unroll
    for (int m = 1; m <= 32; m <<= 1) s += __shfl_xor(s, m, 64);
    float inv = 1.0f / fmaxf(sqrtf(s), 1e-8f);
    if (lane == 0) {
        inv_norm[row] = inv;
        best[row] = 0ull;   // below any real packed key
    }
    float sc = inv * 127.0f;   // int8 symmetric quant; |x_norm|<=1 -> no clamp
    int q0 = __float2int_rn(a.x*sc), q1 = __float2int_rn(a.y*sc);
    int q2 = __float2int_rn(a.z*sc), q3 = __float2int_rn(a.w*sc);
    int q4 = __float2int_rn(b.x*sc), q5 = __float2int_rn(b.y*sc);
    int q6 = __float2int_rn(b.z*sc), q7 = __float2int_rn(b.w*sc);
    int lo = (q0 & 255) | ((q1 & 255) << 8) | ((q2 & 255) << 16) | ((q3 & 255) << 24);
    int hi = (q4 & 255) | ((q5 & 255) << 8) | ((q6 & 255) << 16) | ((q7 & 255) << 24);
    // cols [lane*8, lane*8+8): kc = lane>>3, slot = (lane>>1)&3, o = (lane&1)*8
    unsigned char* dst = xb + (size_t)(lane >> 3) * 524288
                            + (size_t)((lane >> 1) & 3) * 131072
                            + (size_t)row * 16 + (lane & 1) * 8;
    *(int2*)dst = make_int2(lo, hi);
}

// ---- kernel 2: 256x256-tile int8 GEMM + argmax (R21) -----------------------
// Model (fits R15-R20): staged bytes served at ~20 GB/s/CU regardless of
// depth/occupancy/affinity -> scatter-limited VMEM ingest. R21:
//  (a) contiguous staging from K-major X_t: every async16 = one coalesced
//      1KB burst; LDS dest linear [kc2][s][256][16]; frag ds_reads are
//      conflict-free WITHOUT swizzle (16B row stride -> 2 lanes/bank).
//  (b) 256x256 tiles, BK=128: bytes/dot 5.9 -> 4.0 (203 -> 135 MB), 4
//      K-steps, 528 blocks = 66/XCD exactly (pad-free column affinity:
//      XCD x owns cols {x, 31-x, x+8, 23-x}).
//  8 waves (2x4), per-wave 128x64 subtile, acc 8x4 i32x4 = 128 VGPR;
//  1 block/CU (LDS 128KB) -- occupancy shown harmless in R19.
// u32 tile-local keys (R17): |i8 dot| <= 512*127^2 < 2^23, lidx < 256 ->
// key = (dot+0x800000)<<8 | (255-lidx); v_max_u32 + 32-bit shfl.
// NOTE (R12-R14): do NOT fuse the neighbor gather into this kernel.

__global__ __launch_bounds__(512, 2) void gemm_argmax(
        const unsigned char* __restrict__ X, u64* __restrict__ best) {
    __shared__ unsigned char smem[131072];
    unsigned char* As = smem;               // [2][2][4][256][16] = 2 x 32 KB
    unsigned char* Bs = smem + 65536;       // [2][2][4][256][16] = 2 x 32 KB
    unsigned int* rmerge = (unsigned int*)smem;          // [256][4] 4KB alias
    unsigned int* cmerge = (unsigned int*)(smem + 4096); // [256][2] 2KB alias

    // column-affinity decode: XCD x = l&7 owns cols {x, 31-x, x+8, 23-x},
    // lengths {x+1, 32-x, x+9, 24-x}, cum {x+1, 33, 42+x, 66}.
    const int l    = blockIdx.x;
    const int x    = l & 7;
    const int rank = l >> 3;            // 0..65, no padding
    int bi, bj;
    if (rank <= x)           { bj = x;      bi = rank; }
    else if (rank < 33)      { bj = 31 - x; bi = rank - (x + 1); }
    else if (rank < 42 + x)  { bj = x + 8;  bi = rank - 33; }
    else                     { bj = 23 - x; bi = rank - (42 + x); }
    const int m0 = bi * TB;
    const int n0 = bj * TB;

    const int t    = threadIdx.x;
    const int lane = t & 63;
    const int w    = t >> 6;            // 0..7
    const int wm   = w >> 2;            // row half    (128 rows)
    const int wn   = w & 3;             // col quarter (64 cols)
    const int qr   = lane & 15;
    const int quad = lane >> 4;

    const int tl = t & 255;             // 0..255 (position within half-block)
    const int th = t >> 8;              // 0..1

    // stage one K-step (BK=128 = 2 kc-chunks x 4 slots = 8 segments of 4KB
    // per operand). Round j covers segments e = 2j+th; src contiguous 4KB.
    #define STAGE(buf, t4)                                                  \
        do {                                                                \
            _Pragma("unroll")                                               \
            for (int j = 0; j < 4; j++) {                                   \
                const int e = 2 * j + th;                                   \
                async16(As + (buf) * 32768 + e * 4096 + tl * 16,            \
                        X + (size_t)(2 * (t4) + (e >> 2)) * 524288          \
                          + (size_t)(e & 3) * 131072                        \
                          + (size_t)m0 * 16 + tl * 16);                     \
            }                                                               \
            _Pragma("unroll")                                               \
            for (int j = 0; j < 4; j++) {                                   \
                const int e = 2 * j + th;                                   \
                async16(Bs + (buf) * 32768 + e * 4096 + tl * 16,            \
                        X + (size_t)(2 * (t4) + (e >> 2)) * 524288          \
                          + (size_t)(e & 3) * 131072                        \
                          + (size_t)n0 * 16 + tl * 16);                     \
            }                                                               \
        } while (0)

    i32x4 accm[8][4];
    #pragma unroll
    for (int mi = 0; mi < 8; mi++)
        #pragma unroll
        for (int ni = 0; ni < 4; ni++)
            accm[mi][ni] = (i32x4){0, 0, 0, 0};

    STAGE(0, 0);
    #pragma unroll
    for (int t4 = 0; t4 < 4; t4++) {
        const int buf = t4 & 1;
        if (t4 < 3) {
            STAGE(buf ^ 1, t4 + 1);
            asm volatile("s_waitcnt vmcnt(16)" ::: "memory");  // buf[cur] landed
        } else {
            asm volatile("s_waitcnt vmcnt(0)" ::: "memory");
        }
        __builtin_amdgcn_s_barrier();

        #pragma unroll
        for (int ks = 0; ks < 2; ks++) {
            const unsigned char* pA = As + buf * 32768 + ks * 16384
                                    + quad * 4096 + (wm * 128 + qr) * 16;
            const unsigned char* pB = Bs + buf * 32768 + ks * 16384
                                    + quad * 4096 + (wn * 64 + qr) * 16;
            i32x4 av[8], bv[4];
            #pragma unroll
            for (int mi = 0; mi < 8; mi++)
                av[mi] = *(const i32x4*)(pA + mi * 256);
            #pragma unroll
            for (int ni = 0; ni < 4; ni++)
                bv[ni] = *(const i32x4*)(pB + ni * 256);
            #pragma unroll
            for (int mi = 0; mi < 8; mi++)
                #pragma unroll
                for (int ni = 0; ni < 4; ni++)
                    accm[mi][ni] = __builtin_amdgcn_mfma_i32_16x16x64_i8(
                        av[mi], bv[ni], accm[mi][ni], 0, 0, 0);
        }

        asm volatile("" ::: "memory");   // keep frag reads above this barrier
        __builtin_amdgcn_s_barrier();    // reads consumed; safe to overwrite
    }
    #undef STAGE

    // ---- epilogue: u32 tile-local keys ------------------------------------
    const int colg_base = n0 + wn * 64 + qr;          // + ni*16

    // row-side argmax over this wave's 64 cols (diag masked)
    #pragma unroll
    for (int mi = 0; mi < 8; mi++) {
        #pragma unroll
        for (int r = 0; r < 4; r++) {
            const int rowl = wm * 128 + mi * 16 + quad * 4 + r;
            const int rowg = m0 + rowl;
            unsigned key = 0u;
            #pragma unroll
            for (int ni = 0; ni < 4; ni++) {
                const int colg = colg_base + ni * 16;
                const unsigned lcol = (unsigned)(wn * 64 + ni * 16 + qr);
                unsigned k = (((unsigned)accm[mi][ni][r] + 0x800000u) << 8)
                           | (255u - lcol);
                k = (colg == rowg) ? 0u : k;
                key = key > k ? key : k;
            }
            #pragma unroll
            for (int m = 1; m <= 8; m <<= 1) {
                unsigned o = (unsigned)__shfl_xor((int)key, m, 64);
                key = key > o ? key : o;
            }
            if (qr == 0) rmerge[rowl * 4 + wn] = key;
        }
    }

    // col-side argmax (symmetry; diag masked here too)
    #pragma unroll
    for (int ni = 0; ni < 4; ni++) {
        const int colg = colg_base + ni * 16;
        unsigned key = 0u;
        #pragma unroll
        for (int mi = 0; mi < 8; mi++) {
            #pragma unroll
            for (int r = 0; r < 4; r++) {
                const unsigned lrow = (unsigned)(wm * 128 + mi * 16 + quad * 4 + r);
                const int rowg = m0 + (int)lrow;
                unsigned k = (((unsigned)accm[mi][ni][r] + 0x800000u) << 8)
                           | (255u - lrow);
                k = (rowg == colg) ? 0u : k;
                key = key > k ? key : k;
            }
        }
        unsigned o = (unsigned)__shfl_xor((int)key, 16, 64);
        key = key > o ? key : o;
        o = (unsigned)__shfl_xor((int)key, 32, 64);
        key = key > o ? key : o;
        if (quad == 0) cmerge[(wn * 64 + ni * 16 + qr) * 2 + wm] = key;
    }
    __syncthreads();

    if (t < TB) {
        unsigned a0 = rmerge[t * 4], a1 = rmerge[t * 4 + 1];
        unsigned a2 = rmerge[t * 4 + 2], a3 = rmerge[t * 4 + 3];
        unsigned k01 = a0 > a1 ? a0 : a1;
        unsigned k23 = a2 > a3 ? a2 : a3;
        unsigned k = k01 > k23 ? k01 : k23;
        // expand to global u64 key: bd32 = dot + 2^31, tie-break smaller col
        unsigned bd32 = (k >> 8) + 0x7F800000u;
        unsigned colg = (unsigned)(n0 + 255) - (k & 255u);
        u64 kk = ((u64)bd32 << 32) | (u64)(0xFFFFFFFFu - colg);
        atomicMax(&best[m0 + t], kk);
    } else {
        const int tt = t - TB;
        unsigned c0 = cmerge[tt * 2], c1 = cmerge[tt * 2 + 1];
        unsigned k = c0 > c1 ? c0 : c1;
        unsigned bd32 = (k >> 8) + 0x7F800000u;
        unsigned rowg = (unsigned)(m0 + 255) - (k & 255u);
        u64 kk = ((u64)bd32 << 32) | (u64)(0xFFFFFFFFu - rowg);
        atomicMax(&best[n0 + tt], kk);
    }
}

// ---- kernel 3: exact fp32 distance + fused mean (256-block cheap ticket) ---

__global__ __launch_bounds__(256) void neighbor_reduce(
        const float* __restrict__ in, const float* __restrict__ inv_norm,
        const u64* __restrict__ best, float* __restrict__ acc,
        int* __restrict__ cnt, float* __restrict__ out, int B) {
    const int wave = threadIdx.x >> 6;
    const int lane = threadIdx.x & 63;
    float lsum = 0.f;
    #pragma unroll
    for (int rr = 0; rr < 8; rr++) {
        const int row = blockIdx.x * 32 + wave * 8 + rr;
        u64 k   = best[row];
        int nbr = (int)(0xFFFFFFFFu - (unsigned)(k & 0xFFFFFFFFull));
        float ir  = inv_norm[row];
        float inb = inv_norm[nbr];
        const float4* rp = (const float4*)(in + (size_t)row * D_DIM) + lane * 2;
        const float4* np = (const float4*)(in + (size_t)nbr * D_DIM) + lane * 2;
        float4 r0 = rp[0], r1 = rp[1], q0 = np[0], q1 = np[1];
        float d0 = r0.x*ir - q0.x*inb + 1e-8f, d1 = r0.y*ir - q0.y*inb + 1e-8f;
        float d2 = r0.z*ir - q0.z*inb + 1e-8f, d3 = r0.w*ir - q0.w*inb + 1e-8f;
        float d4 = r1.x*ir - q1.x*inb + 1e-8f, d5 = r1.y*ir - q1.y*inb + 1e-8f;
        float d6 = r1.z*ir - q1.z*inb + 1e-8f, d7 = r1.w*ir - q1.w*inb + 1e-8f;
        float s = d0*d0 + d1*d1 + d2*d2 + d3*d3 + d4*d4 + d5*d5 + d6*d6 + d7*d7;
        #pragma unroll
        for (int m = 1; m <= 32; m <<= 1) s += __shfl_xor(s, m, 64);
        if (lane == 0) lsum += logf(sqrtf(s) + 1e-8f);
    }
    __shared__ float sb[4];
    if (lane == 0) sb[wave] = lsum;
    __syncthreads();
    if (threadIdx.x == 0) {
        float partial = sb[0] + sb[1] + sb[2] + sb[3];
        atomicAdd(acc, partial);
        __threadfence();
        int done = atomicAdd(cnt, 1);
        if (done == gridDim.x - 1) {
            __threadfence();
            float tot = atomicAdd(acc, 0.0f);   // device-scope read of final sum
            out[0] = -tot / (float)B;
        }
    }
}

// ---- launch ----------------------------------------------------------------

extern "C" void kernel_launch(void* const* d_in, const int* in_sizes, int n_in,
                              void* d_out, int out_size, void* d_ws, size_t ws_size,
                              hipStream_t stream) {
    const float* in = (const float*)d_in[0];
    const int B = in_sizes[0] / D_DIM;          // 8192
    const int nblk = 528;                       // 66 ranks x 8 XCDs, pad-free

    char* w = (char*)d_ws;
    unsigned char* xb = (unsigned char*)w;                     // B*D int8 (K-major)
    float* invn = (float*)(w + (size_t)B * D_DIM);
    u64*   best = (u64*)(w + (size_t)B * D_DIM + (size_t)B * 4);
    float* acc  = (float*)(w + (size_t)B * D_DIM + (size_t)B * 4 + (size_t)B * 8);
    int*   cnt  = (int*)(acc + 1);
    float* out  = (float*)d_out;

    normalize_rows<<<B / 4, 256, 0, stream>>>(in, xb, invn, best, acc, cnt);
    gemm_argmax<<<nblk, 512, 0, stream>>>(xb, best);
    neighbor_reduce<<<B / 32, 256, 0, stream>>>(in, invn, best, acc, cnt, out, B);
}